// Round 5
// baseline (10427.923 us; speedup 1.0000x reference)
//
#include <hip/hip_runtime.h>
#include <hip/hip_bf16.h>
#include <math.h>
#include <stdint.h>

// ---------------- constants ----------------
#define T_STEPS 191      // 200 - 9
#define NB1 31
#define YS 13
#define HP 264           // h/hn LDS pitch (floats)

typedef __attribute__((ext_vector_type(8))) short short8;
typedef __attribute__((ext_vector_type(4))) float floatx4;

__device__ __forceinline__ float sigmoid_(float x) { return 1.f / (1.f + expf(-x)); }
__device__ __forceinline__ unsigned short bf16_(float x) {
    __hip_bfloat16 b = __float2bfloat16(x);
    return *reinterpret_cast<unsigned short*>(&b);
}

// ---------------- tiled fp32 GEMM: C = act(A @ B + bias) ----------------
template <bool GATHER, bool RELU>
__global__ __launch_bounds__(256) void gemm_tiled(
    const float* __restrict__ A, const float* __restrict__ B,
    const float* __restrict__ bias, float* __restrict__ C,
    int M, int N, int K)
{
    __shared__ float As[16][65];
    __shared__ float Bs[16][65];
    const int tid = threadIdx.x;
    const int tm = tid >> 4, tn = tid & 15;
    const int rowBase = blockIdx.y * 64;
    const int colBase = blockIdx.x * 64;
    float acc[4][4] = {};
    for (int kt = 0; kt < K; kt += 16) {
        #pragma unroll
        for (int l = 0; l < 4; ++l) {
            const int idx = tid + l * 256;
            const int kk = idx & 15, rr = idx >> 4;
            const int row = rowBase + rr;
            float v = 0.f;
            if (row < M) {
                if (GATHER) {
                    const int t = row / 30, i = row - t * 30;
                    const int k = kt + kk;
                    const int src = (k < 256) ? ((t * NB1 + i + 1) * 256 + k)
                                              : (t * NB1 * 256 + (k - 256));
                    v = A[src];
                } else {
                    v = A[(size_t)row * K + kt + kk];
                }
            }
            As[kk][rr] = v;
            const int nn = idx & 63, k2 = idx >> 6;
            Bs[k2][nn] = B[(size_t)(kt + k2) * N + colBase + nn];
        }
        __syncthreads();
        #pragma unroll
        for (int kk = 0; kk < 16; ++kk) {
            float a[4], b[4];
            #pragma unroll
            for (int i = 0; i < 4; ++i) a[i] = As[kk][tm * 4 + i];
            #pragma unroll
            for (int j = 0; j < 4; ++j) b[j] = Bs[kk][tn * 4 + j];
            #pragma unroll
            for (int i = 0; i < 4; ++i)
                #pragma unroll
                for (int j = 0; j < 4; ++j)
                    acc[i][j] = fmaf(a[i], b[j], acc[i][j]);
        }
        __syncthreads();
    }
    #pragma unroll
    for (int i = 0; i < 4; ++i) {
        const int row = rowBase + tm * 4 + i;
        if (row < M) {
            #pragma unroll
            for (int j = 0; j < 4; ++j) {
                const int col = colBase + tn * 4 + j;
                float v = acc[i][j] + bias[col];
                if (RELU) v = fmaxf(v, 0.f);
                C[(size_t)row * N + col] = v;
            }
        }
    }
}

// ---------------- prep: Whg -> bf16 pre-swizzled into per-wave MFMA B-fragment order ----
// consumer: wave w (0..15), kt (0..7), gate g (0..2), lane (0..63), j (0..7):
//   element = Whg[k][col], k = kt*32 + (lane>>4)*8 + j, col = g*256 + w*16 + (lane&15)
//   at wswz[(((w*8+kt)*3+g)*64 + lane)*8 + j]
__global__ __launch_bounds__(256) void prep_wswz(const float* __restrict__ Whg,
                                                 unsigned short* __restrict__ wswz)
{
    const int idx = blockIdx.x * 256 + threadIdx.x;
    if (idx >= 196608) return;
    const int j = idx & 7, lane = (idx >> 3) & 63, rest = idx >> 9;
    const int g = rest % 3, ktw = rest / 3, kt = ktw & 7, w = ktw >> 3;
    const int k = kt * 32 + ((lane >> 4) << 3) + j;
    const int col = g * 256 + w * 16 + (lane & 15);
    wswz[idx] = bf16_(Whg[k * 768 + col]);
}

// WpT[37][544]: WpT[d][k] = Wpbox[k][d] for d<36; row 36 = W_out
__global__ __launch_bounds__(256) void prep_wpt(const float* __restrict__ Wpbox,
                                                const float* __restrict__ Wout,
                                                float* __restrict__ WpT)
{
    const int idx = blockIdx.x * 256 + threadIdx.x;
    if (idx >= 37 * 544) return;
    const int d = idx / 544, k = idx - d * 544;
    WpT[idx] = (d < 36) ? Wpbox[k * 36 + d] : Wout[k];
}

// combined biases: r/z gates get bx+bh (additive), n gate keeps bx only
__global__ void prep_bias(const float* __restrict__ bxg, const float* __restrict__ bhg,
                          const float* __restrict__ bxc, const float* __restrict__ bhc,
                          float* __restrict__ biasg, float* __restrict__ biasc)
{
    const int t = threadIdx.x;
    if (t < 768) biasg[t] = bxg[t] + (t < 512 ? bhg[t] : 0.f);
    if (t < 96)  biasc[t] = bxc[t] + (t < 64 ? bhc[t] : 0.f);
}

// ---------------- per-(t,obj) small precompute ----------------
__global__ __launch_bounds__(256) void precomp_kernel(
    const float* __restrict__ y,
    const float* __restrict__ Wbb, const float* __restrict__ bbb,
    const float* __restrict__ Wdd, const float* __restrict__ bdd,
    const float* __restrict__ Wproj, const float* __restrict__ bproj,
    const float* __restrict__ Wxc, const float* __restrict__ biasc,
    const float* __restrict__ Wpbox, const float* __restrict__ bpbox,
    const float* __restrict__ Wout, const float* __restrict__ bout,
    float* __restrict__ gxc, float* __restrict__ pbox_b, float* __restrict__ logit_b)
{
    const int m = blockIdx.x;
    const int tid = threadIdx.x;
    __shared__ float bf[256], df[256], xcs[32], yl[16];
    if (tid < YS) yl[tid] = y[m * YS + tid];
    __syncthreads();
    const float invnorm[4] = {1.f/1920.f, 1.f/1200.f, 1.f/1920.f, 1.f/1200.f};
    {
        float s = bbb[tid];
        s = fmaf(yl[1] * invnorm[0], Wbb[0 * 256 + tid], s);
        s = fmaf(yl[2] * invnorm[1], Wbb[1 * 256 + tid], s);
        s = fmaf(yl[3] * invnorm[2], Wbb[2 * 256 + tid], s);
        s = fmaf(yl[4] * invnorm[3], Wbb[3 * 256 + tid], s);
        s = fmaf(yl[6],              Wbb[4 * 256 + tid], s);
        bf[tid] = fmaxf(s, 0.f);
    }
    {
        float s = bdd[tid];
        #pragma unroll
        for (int k = 0; k < 6; ++k) s = fmaf(yl[7 + k], Wdd[k * 256 + tid], s);
        df[tid] = fmaxf(s, 0.f);
    }
    __syncthreads();
    {
        const int c = tid >> 3, p = tid & 7;
        float s = 0.f;
        for (int k = p; k < 256; k += 8) s = fmaf(df[k], Wproj[k * 32 + c], s);
        s += __shfl_xor(s, 1); s += __shfl_xor(s, 2); s += __shfl_xor(s, 4);
        if (p == 0) xcs[c] = s + bproj[c];
    }
    __syncthreads();
    if (tid < 96) {
        float s = biasc[tid];
        #pragma unroll
        for (int k = 0; k < 32; ++k) s = fmaf(xcs[k], Wxc[k * 96 + tid], s);
        gxc[m * 96 + tid] = s;
    }
    {
        const int d = tid >> 2, p = tid & 3;
        if (d < 37) {
            float s = 0.f;
            if (d < 36) {
                for (int k = p; k < 256; k += 4) s = fmaf(bf[k], Wpbox[(256 + k) * 36 + d], s);
            } else {
                for (int k = p; k < 256; k += 4) s = fmaf(bf[k], Wout[256 + k], s);
            }
            s += __shfl_xor(s, 1); s += __shfl_xor(s, 2);
            if (p == 0) {
                if (d < 36) pbox_b[m * 36 + d] = s + bpbox[d];
                else        logit_b[m] = s + bout[0];
            }
        }
    }
}

// ---------------- sequential recurrence: ONE persistent block, 1024 threads, MFMA ----
__global__ __launch_bounds__(1024) void seq_kernel(
    const float* __restrict__ y,
    const float* __restrict__ gxg,      // 5730 x 768 (r/z incl bx+bh, n incl bx)
    const float* __restrict__ gxc,      // 5730 x 96
    const float* __restrict__ pbox_b,   // 5730 x 36
    const float* __restrict__ logit_b,  // 5730
    const unsigned short* __restrict__ wswz, // pre-swizzled Whg bf16 fragments
    const float* __restrict__ bhg,      // 768 (n-part used)
    const float* __restrict__ Whc,      // 32 x 96
    const float* __restrict__ bhc,      // 96 (n-part used)
    const float* __restrict__ WpT,      // 37 x 544 transposed heads weights
    float* __restrict__ out)
{
    const int tid  = threadIdx.x;
    const int lane = tid & 63, w = tid >> 6;
    const int quad = lane >> 4, l15 = lane & 15;

    __shared__ float h_s[30 * HP];           // h state (becomes h2 then h_{t+1} in place)
    __shared__ float hn_s[30 * HP];          // GRU output (pre-attention), for heads
    __shared__ unsigned short hbf[32 * 256]; // bf16 of h (A/B fragments); rows 30,31 = 0
    __shared__ unsigned short h2bfT[256 * 32];
    __shared__ unsigned short attwbf[32 * 32];
    __shared__ float whc_s[32 * 96];
    __shared__ float hcb[2][30 * 33];
    __shared__ float hcn_s[30 * 33];
    __shared__ float S_s[32 * 34];
    __shared__ float attw2[30 * 32];
    __shared__ float sc2[30 * 32];
    __shared__ float pbl[30 * 40];
    __shared__ float bhn_s[256], bhcn_s[32];
    __shared__ float actsf[2][32];
    __shared__ float red[32];

    // ---- init ----
    for (int e = tid; e < 30 * HP; e += 1024) { h_s[e] = 0.f; hn_s[e] = 0.f; }
    for (int e = tid; e < 32 * 256; e += 1024) hbf[e] = 0;
    for (int e = tid; e < 256 * 32; e += 1024) h2bfT[e] = 0;
    for (int e = tid; e < 32 * 32; e += 1024) attwbf[e] = 0;
    for (int e = tid; e < 32 * 96; e += 1024) whc_s[e] = Whc[e];
    for (int e = tid; e < 30 * 33; e += 1024) hcb[0][e] = 0.f;
    if (tid < 256) bhn_s[tid] = bhg[512 + tid];
    if (tid < 32)  bhcn_s[tid] = bhc[64 + tid];
    if (tid < 32)  actsf[0][tid] = (tid < 30 && y[tid * YS] != 0.f) ? 1.f : 0.f;
    __syncthreads();

    float bacc = 0.f, oacc = 0.f;
    const float invnorm[4] = {1.f/1920.f, 1.f/1200.f, 1.f/1920.f, 1.f/1200.f};

    for (int t = 0; t < T_STEPS; ++t) {
        const int par = t & 1;
        const float* acts = actsf[par];
        float* hcold = hcb[par];
        float* hcnew = hcb[1 - par];

        // ======== S0: gate GEMM (MFMA, B-frags direct from global) + in-wave combine ====
        {
            floatx4 accR[2] = {{0,0,0,0},{0,0,0,0}};
            floatx4 accZ[2] = {{0,0,0,0},{0,0,0,0}};
            floatx4 accN[2] = {{0,0,0,0},{0,0,0,0}};
            const unsigned short* wb = wswz + ((w * 24) << 9) + (lane << 3);
            #pragma unroll
            for (int kt = 0; kt < 8; ++kt) {
                const short8 b0 = *(const short8*)(wb + ((kt * 3 + 0) << 9));
                const short8 b1 = *(const short8*)(wb + ((kt * 3 + 1) << 9));
                const short8 b2 = *(const short8*)(wb + ((kt * 3 + 2) << 9));
                const short8 a0 = *(const short8*)&hbf[(l15 << 8)        + (kt << 5) + (quad << 3)];
                const short8 a1 = *(const short8*)&hbf[((16 + l15) << 8) + (kt << 5) + (quad << 3)];
                accR[0] = __builtin_amdgcn_mfma_f32_16x16x32_bf16(a0, b0, accR[0], 0, 0, 0);
                accR[1] = __builtin_amdgcn_mfma_f32_16x16x32_bf16(a1, b0, accR[1], 0, 0, 0);
                accZ[0] = __builtin_amdgcn_mfma_f32_16x16x32_bf16(a0, b1, accZ[0], 0, 0, 0);
                accZ[1] = __builtin_amdgcn_mfma_f32_16x16x32_bf16(a1, b1, accZ[1], 0, 0, 0);
                accN[0] = __builtin_amdgcn_mfma_f32_16x16x32_bf16(a0, b2, accN[0], 0, 0, 0);
                accN[1] = __builtin_amdgcn_mfma_f32_16x16x32_bf16(a1, b2, accN[1], 0, 0, 0);
            }
            const int c = (w << 4) + l15;
            #pragma unroll
            for (int mt = 0; mt < 2; ++mt) {
                #pragma unroll
                for (int reg = 0; reg < 4; ++reg) {
                    const int i = mt * 16 + quad * 4 + reg;
                    if (i < 30) {
                        const size_t m768 = (size_t)(t * 30 + i) * 768;
                        const float rv = accR[mt][reg] + gxg[m768 + c];
                        const float zv = accZ[mt][reg] + gxg[m768 + 256 + c];
                        const float nh = accN[mt][reg] + bhn_s[c];
                        const float xn = gxg[m768 + 512 + c];
                        const float rg = sigmoid_(rv), zg = sigmoid_(zv);
                        const float ng = tanhf(xn + rg * nh);
                        const float hold = h_s[i * HP + c];
                        const float hnv = (1.f - zg) * ng + zg * hold;
                        hn_s[i * HP + c] = hnv;
                        h_s[i * HP + c] = (acts[i] != 0.f) ? hnv : hold;  // h2
                    }
                }
            }
        }
        __syncthreads();  // B1: hn, h2 ready

        // ======== S1: pack h2 -> hbf + h2bfT; hc-GRU ========
        for (int e = tid; e < 7680; e += 1024) {
            const int i = e >> 8, k = e & 255;
            const unsigned short v = bf16_(h_s[i * HP + k]);
            hbf[(i << 8) + k] = v;
            h2bfT[(k << 5) + i] = v;
        }
        if (tid < 960) {
            const int i = tid >> 5, cc = tid & 31;
            const size_t m96 = (size_t)(t * 30 + i) * 96;
            float ar = gxc[m96 + cc], az = gxc[m96 + 32 + cc], nh = bhcn_s[cc];
            const float xn = gxc[m96 + 64 + cc];
            #pragma unroll
            for (int k = 0; k < 32; ++k) {
                const float hk = hcold[i * 33 + k];
                ar = fmaf(hk, whc_s[k * 96 + cc], ar);
                az = fmaf(hk, whc_s[k * 96 + 32 + cc], az);
                nh = fmaf(hk, whc_s[k * 96 + 64 + cc], nh);
            }
            const float rg = sigmoid_(ar), zg = sigmoid_(az);
            const float ng = tanhf(xn + rg * nh);
            const float hold = hcold[i * 33 + cc];
            const float hv = (1.f - zg) * ng + zg * hold;
            hcn_s[i * 33 + cc] = hv;
            hcnew[i * 33 + cc] = (acts[i] != 0.f) ? hv : hold;  // hc2
        }
        __syncthreads();  // B2

        // ======== S2: attention scores (MFMA, waves 0-3) + heads + hc-scores ========
        if (tid < 256) {
            const int mt = w >> 1, nt = w & 1;
            floatx4 sacc = {0, 0, 0, 0};
            #pragma unroll
            for (int kt = 0; kt < 8; ++kt) {
                const short8 a = *(const short8*)&hbf[((mt * 16 + l15) << 8) + (kt << 5) + (quad << 3)];
                const short8 b = *(const short8*)&hbf[((nt * 16 + l15) << 8) + (kt << 5) + (quad << 3)];
                sacc = __builtin_amdgcn_mfma_f32_16x16x32_bf16(a, b, sacc, 0, 0, 0);
            }
            #pragma unroll
            for (int reg = 0; reg < 4; ++reg)
                S_s[(mt * 16 + quad * 4 + reg) * 34 + nt * 16 + l15] = sacc[reg];
        }
        for (int jo = tid; jo < 1110; jo += 1024) {   // heads: 37 outs x 30 rows
            const int d = jo / 30, i = jo - d * 30;
            const int m = t * 30 + i;
            float s = (d < 36) ? pbox_b[m * 36 + d] : logit_b[m];
            const float4* wp4 = (const float4*)(WpT + d * 544);
            const float4* hn4 = (const float4*)(hn_s + i * HP);
            for (int k4 = 0; k4 < 64; ++k4) {
                const float4 wv = wp4[k4], hv = hn4[k4];
                s = fmaf(hv.x, wv.x, s); s = fmaf(hv.y, wv.y, s);
                s = fmaf(hv.z, wv.z, s); s = fmaf(hv.w, wv.w, s);
            }
            #pragma unroll
            for (int k = 0; k < 32; ++k) s = fmaf(hcn_s[i * 33 + k], WpT[d * 544 + 512 + k], s);
            pbl[i * 40 + d] = s;
        }
        for (int jo = tid; jo < 900; jo += 1024) {    // hc-attention scores
            const int i = jo / 30, j = jo - i * 30;
            float s = 0.f;
            #pragma unroll
            for (int k = 0; k < 32; ++k) s = fmaf(hcnew[i * 33 + k], hcnew[j * 33 + k], s);
            sc2[i * 32 + j] = (acts[j] != 0.f) ? s * 0.17677669529663687f : -1e9f;
        }
        __syncthreads();  // B3

        // ======== S3: softmaxes + losses ========
        if (tid < 30) {           // h softmax -> attwbf (bf16)
            const int i = tid;
            float mx = -1e30f;
            for (int j = 0; j < 30; ++j) {
                const float s = (acts[j] != 0.f) ? S_s[i * 34 + j] * 0.0625f : -1e9f;
                mx = fmaxf(mx, s);
            }
            float sum = 0.f;
            for (int j = 0; j < 30; ++j) {
                const float s = (acts[j] != 0.f) ? S_s[i * 34 + j] * 0.0625f : -1e9f;
                sum += expf(s - mx);
            }
            const float inv = 1.f / sum;
            for (int j = 0; j < 30; ++j) {
                const float s = (acts[j] != 0.f) ? S_s[i * 34 + j] * 0.0625f : -1e9f;
                attwbf[i * 32 + j] = bf16_(expf(s - mx) * inv);
            }
        } else if (tid >= 32 && tid < 62) {  // hc softmax -> attw2 (f32)
            const int i = tid - 32;
            float mx = -1e30f;
            for (int j = 0; j < 30; ++j) mx = fmaxf(mx, sc2[i * 32 + j]);
            float sum = 0.f;
            for (int j = 0; j < 30; ++j) sum += expf(sc2[i * 32 + j] - mx);
            const float inv = 1.f / sum;
            for (int j = 0; j < 30; ++j) attw2[i * 32 + j] = expf(sc2[i * 32 + j] - mx) * inv;
        }
        for (int jo = tid; jo < 1110; jo += 1024) {   // losses (register accumulate)
            const int d = jo / 30, i = jo - d * 30;
            const float af = acts[i];
            if (d < 36) {
                const int s4 = d >> 2, cc = d & 3;
                const float fut = y[((t + 1 + s4) * 30 + i) * YS + 1 + cc] * invnorm[cc];
                const float dd = pbl[i * 40 + d] - fut;
                const float ad = fabsf(dd);
                bacc = fmaf(((ad < 1.f) ? 0.5f * dd * dd : (ad - 0.5f)) * (1.f / 36.f), af, bacc);
            } else {
                const float l = pbl[i * 40 + 36];
                const float tgt = y[(t * 30 + i) * YS + 5];
                const float bce = fmaxf(l, 0.f) - l * tgt + log1pf(expf(-fabsf(l)));
                oacc = fmaf(0.05f * bce, af, oacc);
            }
        }
        __syncthreads();  // B4

        // ======== S4: O = attw @ H2 via O^T = H2^T @ attw^T (MFMA) + hc-out compute ====
        {
            #pragma unroll
            for (int nt = 0; nt < 2; ++nt) {
                floatx4 o = {0, 0, 0, 0};
                const short8 a = *(const short8*)&h2bfT[((w * 16 + l15) << 5) + (quad << 3)];
                const short8 b = *(const short8*)&attwbf[((nt * 16 + l15) << 5) + (quad << 3)];
                o = __builtin_amdgcn_mfma_f32_16x16x32_bf16(a, b, o, 0, 0, 0);
                const int i = nt * 16 + l15;
                if (i < 30 && acts[i] != 0.f) {
                    #pragma unroll
                    for (int reg = 0; reg < 4; ++reg)
                        h_s[i * HP + (w * 16 + quad * 4 + reg)] = o[reg];
                }
            }
        }
        float hco = 0.f;
        if (tid < 960) {
            const int i = tid >> 5, c = tid & 31;
            #pragma unroll 6
            for (int j = 0; j < 30; ++j) hco = fmaf(attw2[i * 32 + j], hcnew[j * 33 + c], hco);
        }
        __syncthreads();  // B5

        // ======== S5: hc-out write + pack h_{t+1} -> hbf + next acts ========
        if (tid < 960) {
            const int i = tid >> 5, c = tid & 31;
            if (acts[i] != 0.f) hcnew[i * 33 + c] = hco;
        }
        for (int e = tid; e < 7680; e += 1024) {
            const int i = e >> 8, k = e & 255;
            hbf[(i << 8) + k] = bf16_(h_s[i * HP + k]);
        }
        if (tid < 32) {
            const int tn = t + 1;
            float v = 0.f;
            if (tn < T_STEPS && tid < 30) v = (y[(tn * 30 + tid) * YS] != 0.f) ? 1.f : 0.f;
            actsf[tn & 1][tid] = v;
        }
        __syncthreads();  // B6
    }

    // ---- final reduction ----
    #pragma unroll
    for (int o = 1; o < 64; o <<= 1) {
        bacc += __shfl_xor(bacc, o);
        oacc += __shfl_xor(oacc, o);
    }
    if (lane == 0) { red[w] = bacc; red[16 + w] = oacc; }
    __syncthreads();
    if (tid == 0) {
        float b = 0.f, o = 0.f;
        for (int k = 0; k < 16; ++k) { b += red[k]; o += red[16 + k]; }
        out[0] = o + 1.3f * b;
    }
}

// ---------------- launch ----------------
extern "C" void kernel_launch(void* const* d_in, const int* in_sizes, int n_in,
                              void* d_out, int out_size, void* d_ws, size_t ws_size,
                              hipStream_t stream) {
    (void)in_sizes; (void)n_in; (void)out_size; (void)ws_size;
    const float* y      = (const float*)d_in[1];
    const float* flow   = (const float*)d_in[3];
    const float* W_rgb  = (const float*)d_in[4];
    const float* b_rgb  = (const float*)d_in[5];
    const float* W_bb   = (const float*)d_in[6];
    const float* b_bb   = (const float*)d_in[7];
    const float* W_dd   = (const float*)d_in[8];
    const float* b_dd   = (const float*)d_in[9];
    const float* W_proj = (const float*)d_in[10];
    const float* b_proj = (const float*)d_in[11];
    const float* Wx_c   = (const float*)d_in[12];
    const float* Wh_c   = (const float*)d_in[13];
    const float* bx_c   = (const float*)d_in[14];
    const float* bh_c   = (const float*)d_in[15];
    const float* Wx_g   = (const float*)d_in[16];
    const float* Wh_g   = (const float*)d_in[17];
    const float* bx_g   = (const float*)d_in[18];
    const float* bh_g   = (const float*)d_in[19];
    const float* W_out  = (const float*)d_in[20];
    const float* b_out  = (const float*)d_in[21];
    const float* W_pbox = (const float*)d_in[22];
    const float* b_pbox = (const float*)d_in[23];
    float* out = (float*)d_out;

    float* base = (float*)d_ws;
    size_t off = 0;
    float* rgb    = base + off; off += (size_t)5921 * 256;
    float* gxg    = base + off; off += (size_t)5730 * 768;
    float* gxc    = base + off; off += (size_t)5730 * 96;
    float* pboxb  = base + off; off += (size_t)5730 * 36;
    float* logitb = base + off; off += 5730;
    float* biasg  = base + off; off += 768;
    float* biasc  = base + off; off += 96;
    float* WpT    = base + off; off += 37 * 544;
    unsigned short* wswz = (unsigned short*)(base + off); off += 98304;  // 196608 u16

    prep_bias<<<1, 768, 0, stream>>>(bx_g, bh_g, bx_c, bh_c, biasg, biasc);
    prep_wswz<<<768, 256, 0, stream>>>(Wh_g, wswz);
    prep_wpt<<<(37 * 544 + 255) / 256, 256, 0, stream>>>(W_pbox, W_out, WpT);

    // rgb = relu(flow_f @ W_rgb + b_rgb): M=5921, K=4096, N=256
    gemm_tiled<false, true><<<dim3(4, 93), 256, 0, stream>>>(flow, W_rgb, b_rgb, rgb, 5921, 256, 4096);
    // gx_g = comb @ Wx_g + biasg: M=5730, K=512, N=768
    gemm_tiled<true, false><<<dim3(12, 90), 256, 0, stream>>>(rgb, Wx_g, biasg, gxg, 5730, 768, 512);
    precomp_kernel<<<5730, 256, 0, stream>>>(y, W_bb, b_bb, W_dd, b_dd, W_proj, b_proj,
                                             Wx_c, biasc, W_pbox, b_pbox, W_out, b_out,
                                             gxc, pboxb, logitb);
    seq_kernel<<<1, 1024, 0, stream>>>(y, gxg, gxc, pboxb, logitb, wswz, bh_g, Wh_c, bh_c,
                                       WpT, out);
}